// Round 7
// baseline (7472.789 us; speedup 1.0000x reference)
//
#include <hip/hip_runtime.h>
#include <math.h>

#define TT 512
#define BB 32
#define DD 1280

// ---------------------------------------------------------------------------
// Tagged h word: low 32 = float bits, high 32 = step tag.  Agent scope
// (__hip_atomic_*, LLC-coherent) is the only HW-validated visibility path
// (R8 lesson: sc0/local-L2 protocols never became visible -> livelock).
// ---------------------------------------------------------------------------
__device__ __forceinline__ unsigned long long ld_agent_u64(const unsigned long long* p) {
    return __hip_atomic_load(p, __ATOMIC_RELAXED, __HIP_MEMORY_SCOPE_AGENT);
}
__device__ __forceinline__ void st_agent_u64(unsigned long long* p, unsigned long long v) {
    __hip_atomic_store(p, v, __ATOMIC_RELAXED, __HIP_MEMORY_SCOPE_AGENT);
}

// Stamp invalid tags into both slots (guards against workspace garbage that
// could alias a valid tag; t=1 bypasses the ring entirely via h0).
__global__ void init_ring(unsigned long long* __restrict__ ht)
{
    size_t i = (size_t)blockIdx.x * 256 + threadIdx.x;
    if (i < 2 * (size_t)BB * DD)
        st_agent_u64(ht + i, 0xFFFFFFFF00000000ull);
}

// ---------------------------------------------------------------------------
// Shared phase: acc[i][j] = sum_d Sbuf[i*DD+d] * wr[j][k(d)]  (d-split over
// 32 p-lanes), then the R7-validated reduce-scatter tree.  Returns s[0]:
// on lane (u,p) it holds the full dot for (batch ii, row jj) per the lane
// mapping in the caller.  Bitwise-identical tree to R6/R7/R10.
// ---------------------------------------------------------------------------
__device__ __forceinline__ float dot_reduce(const float* __restrict__ Sbuf,
                                            const float4 (&wr)[5][10],
                                            int d0, int p)
{
    float acc[4][5] = {};
#pragma unroll
    for (int k = 0; k < 10; ++k) {
        const int d = d0 + (k << 7);
        float4 a4[4];
#pragma unroll
        for (int i = 0; i < 4; ++i)
            a4[i] = *(const float4*)&Sbuf[i * DD + d];
#pragma unroll
        for (int i = 0; i < 4; ++i)
#pragma unroll
            for (int j = 0; j < 5; ++j)
                acc[i][j] += a4[i].x * wr[j][k].x + a4[i].y * wr[j][k].y
                           + a4[i].z * wr[j][k].z + a4[i].w * wr[j][k].w;
    }
    float s[20];
#pragma unroll
    for (int i = 0; i < 4; ++i)
#pragma unroll
        for (int j = 0; j < 5; ++j)
            s[i * 5 + j] = acc[i][j];
    // m=16: 20 -> 10
#pragma unroll
    for (int i = 0; i < 10; ++i) {
        float send = (p & 16) ? s[i] : s[10 + i];
        float recv = __shfl_xor(send, 16, 64);
        s[i] = ((p & 16) ? s[10 + i] : s[i]) + recv;
    }
    // m=8: 10 -> 5
#pragma unroll
    for (int i = 0; i < 5; ++i) {
        float send = (p & 8) ? s[i] : s[5 + i];
        float recv = __shfl_xor(send, 8, 64);
        s[i] = ((p & 8) ? s[5 + i] : s[i]) + recv;
    }
    // m=4: 5 -> 3 (pad)
    s[5] = 0.f;
#pragma unroll
    for (int i = 0; i < 3; ++i) {
        float send = (p & 4) ? s[i] : s[3 + i];
        float recv = __shfl_xor(send, 4, 64);
        s[i] = ((p & 4) ? s[3 + i] : s[i]) + recv;
    }
    // m=2: 3 -> 2 (pad)
    s[3] = 0.f;
#pragma unroll
    for (int i = 0; i < 2; ++i) {
        float send = (p & 2) ? s[i] : s[2 + i];
        float recv = __shfl_xor(send, 2, 64);
        s[i] = ((p & 2) ? s[2 + i] : s[i]) + recv;
    }
    // m=1: 2 -> 1
    {
        float send = (p & 1) ? s[0] : s[1];
        float recv = __shfl_xor(send, 1, 64);
        s[0] = ((p & 1) ? s[1] : s[0]) + recv;
    }
    return s[0];
}

// ---------------------------------------------------------------------------
// Fused persistent kernel: x-projection GEMM + gated-Elman scan.  R11.
//   8 batch-groups x 4 batches; 32 WGs/group, each owns 40 rows of BOTH
//   Wh and Wx (400 persistent regs/thread; unified VGPR+AGPR file, 1
//   wave/SIMD -> 512-reg budget; LDS round-trip blocks rematerialization).
//   The standalone xproj GEMM (~600us serialized) is gone: XP[t][bb][ee]
//   is computed by the SAME lane decomposition as the scan, during the
//   step's dead window (publish -> verify), from an LDS-staged X[t] slice.
//   Per-step timeline:
//     stage h_{t-1} (from verified v[]) + X[t] -> LDS; barrier
//     scan k-loop + reduce; hn = tanh(xpv_cur + s0)
//     publish hn (tagged 8B agent store)           <- peers' critical path
//     ISSUE 20 tagged loads for h_t (fly during XP phase)
//     XP phase: k-loop + reduce -> xpv_cur for next iter (+bias)
//     VERIFY tags == t; re-load stale words (R6-validated retry shape)
//   Ring-of-2 overwrite safety unchanged: publish of t+1 strictly follows
//   full verify of t (barrier-joined across the WG).  8B tagged words are
//   single-instruction loads/stores -> no torn reads.
// ---------------------------------------------------------------------------
__launch_bounds__(256, 1) __global__
void fused_scan(const float* __restrict__ X, const float* __restrict__ Z,
                const float* __restrict__ H0, const float* __restrict__ Wx,
                const float* __restrict__ Wh, const float* __restrict__ bias,
                float* __restrict__ OUT, unsigned long long* __restrict__ ht)
{
    const int w   = blockIdx.x;
    const int g   = w & 7;        // batch group (label only)
    const int idx = w >> 3;       // e-slice within group, 0..31
    const int b0  = g << 2;       // first of 4 batches
    const int e0  = idx * 40;     // first of 40 W rows
    const int tid = threadIdx.x;
    const int u   = tid >> 5;     // 0..7 -> e-row block
    const int p   = tid & 31;     // d-split lane

    // S: W staging chunks pre-loop, then double-buffered h blocks (2x20KB).
    // Xs: double-buffered X[t] slices (2x20KB).  Total LDS 80 KB.
    __shared__ __align__(16) float S [2 * 4 * DD];
    __shared__ __align__(16) float Xs[2 * 4 * DD];

    // ---- one-time: Wh AND Wx fragments -> 400 persistent regs/thread ----
    // thread (u,p) holds W[e0 + 5u + j][4p + 128k], j<5, k<10, for both.
    const int d0 = p << 2;
    float4 wreg[5][10];    // Wh
    float4 wxreg[5][10];   // Wx
#pragma unroll 1
    for (int c = 0; c < 8; ++c) {
        __syncthreads();
        const float* src = Wh + (size_t)(e0 + 5 * c) * DD;
        for (int i = tid; i < 5 * DD / 4; i += 256)
            ((float4*)S)[i] = ((const float4*)src)[i];
        __syncthreads();
        if (u == c) {
#pragma unroll
            for (int j = 0; j < 5; ++j)
#pragma unroll
                for (int k = 0; k < 10; ++k)
                    wreg[j][k] = *(const float4*)&S[j * DD + d0 + (k << 7)];
        }
    }
#pragma unroll 1
    for (int c = 0; c < 8; ++c) {
        __syncthreads();
        const float* src = Wx + (size_t)(e0 + 5 * c) * DD;
        for (int i = tid; i < 5 * DD / 4; i += 256)
            ((float4*)S)[i] = ((const float4*)src)[i];
        __syncthreads();
        if (u == c) {
#pragma unroll
            for (int j = 0; j < 5; ++j)
#pragma unroll
                for (int k = 0; k < 10; ++k)
                    wxreg[j][k] = *(const float4*)&S[j * DD + d0 + (k << 7)];
        }
    }
    __syncthreads();   // staging region overlaps h buffers; fence before use

    // Output lane mapping (reduce-scatter tree): valid low-3 patterns
    // {0,1,2,4,5} hold row j = {0,1,2,3,4}; bits 3,4 give batch i.
    const int  lo3 = p & 7;
    const bool fin = (lo3 != 3) && (lo3 < 6);
    const int  jj  = (lo3 < 3) ? lo3 : (lo3 - 1);
    const int  ii  = ((p >> 3) & 1) + (((p >> 4) & 1) << 1);
    const int  bb  = b0 + ii;
    const int  ee  = e0 + u * 5 + jj;
    const float bias_lane = bias[ee];

    // ---- prologue: XP[0] (uses Xs buffer 0 = slot for even t) -----------
    {
        const float* xg = X + (size_t)b0 * DD;   // t = 0
#pragma unroll
        for (int i = 0; i < 20; ++i)
            Xs[i * 256 + tid] = xg[i * 256 + tid];
    }
    __syncthreads();
    float xpv_cur = dot_reduce(Xs, wxreg, d0, p) + bias_lane;

    unsigned long long v[20];   // tagged words of h_t, in flight during XP

    for (int t = 1; t <= TT; ++t) {
        const size_t oidx = ((size_t)(t - 1) * BB + bb) * DD + ee;
        float zv = 0.f;
        if (fin) zv = Z[oidx];

        // ---- stage h_{t-1} (verified last iter; t=1: h0) + X[t] ---------
        float* Sh = S + (size_t)(t & 1) * (4 * DD);
        if (t == 1) {
            const float* h0b = H0 + (size_t)b0 * DD;
#pragma unroll
            for (int i = 0; i < 20; ++i)
                Sh[i * 256 + tid] = h0b[i * 256 + tid];
        } else {
#pragma unroll
            for (int i = 0; i < 20; ++i)
                Sh[i * 256 + tid] = __uint_as_float((unsigned)v[i]);
        }
        float* Xb = Xs + (size_t)(t & 1) * (4 * DD);
        if (t < TT) {
            const float* xg = X + ((size_t)t * BB + b0) * DD;
#pragma unroll
            for (int i = 0; i < 20; ++i)
                Xb[i * 256 + tid] = xg[i * 256 + tid];
        }
        __syncthreads();   // the only barrier per step

        // ---- scan phase: h_{t-1} . Wh^T ---------------------------------
        const float s0 = dot_reduce(Sh, wreg, d0, p);
        const float hn = tanhf(xpv_cur + s0);

        // ---- publish FIRST (peers' critical path) -----------------------
        if (fin)
            st_agent_u64(ht + (size_t)(t & 1) * (BB * DD) + (size_t)bb * DD + ee,
                         ((unsigned long long)(unsigned)t << 32) |
                         (unsigned long long)__float_as_uint(hn));

        // ---- issue tagged loads for h_t now; they fly during XP ---------
        const unsigned long long* hn_ =
            ht + (size_t)(t & 1) * (BB * DD) + (size_t)b0 * DD;
        if (t < TT) {
#pragma unroll
            for (int i = 0; i < 20; ++i)
                v[i] = ld_agent_u64(hn_ + i * 256 + tid);
        }

        // ---- output math (fire-and-forget) ------------------------------
        if (fin) {
            const float sg = zv / (1.0f + __expf(-zv));
            OUT[oidx] = hn * sg;
            if (t == TT)
                OUT[(size_t)TT * BB * DD + (size_t)bb * DD + ee] = hn;
        }

        if (t < TT) {
            // ---- XP phase: X[t] . Wx^T (+bias) for the next iteration ---
            xpv_cur = dot_reduce(Xb, wxreg, d0, p) + bias_lane;

            // ---- verify the in-flight h_t words; re-load stale ones -----
            const unsigned need = (unsigned)t;
            bool bad;
            do {
                bad = false;
#pragma unroll
                for (int i = 0; i < 20; ++i)
                    if ((unsigned)(v[i] >> 32) != need) {
                        v[i] = ld_agent_u64(hn_ + i * 256 + tid);
                        bad = true;
                    }
            } while (bad);
        }
    }
}

// ---------------------------------------------------------------------------
extern "C" void kernel_launch(void* const* d_in, const int* in_sizes, int n_in,
                              void* d_out, int out_size, void* d_ws, size_t ws_size,
                              hipStream_t stream) {
    const float* x    = (const float*)d_in[0];  // [T,B,D]
    const float* z    = (const float*)d_in[1];  // [T,B,D]
    const float* h0   = (const float*)d_in[2];  // [B,D]
    const float* Wx   = (const float*)d_in[3];  // [D,D]
    const float* Wh   = (const float*)d_in[4];  // [D,D]
    const float* bias = (const float*)d_in[5];  // [D]
    float* out = (float*)d_out;

    // ws layout: tagged 2-slot h ring 655 KB (XP workspace no longer exists)
    unsigned long long* ht = (unsigned long long*)d_ws;

    init_ring<<<(2 * BB * DD + 255) / 256, 256, 0, stream>>>(ht);
    fused_scan<<<256, 256, 0, stream>>>(x, z, h0, Wx, Wh, bias, out, ht);
}